// Round 1
// baseline (896.795 us; speedup 1.0000x reference)
//
#include <hip/hip_runtime.h>

#define DIMC 1024
#define BATCH 8
#define SEQ 4096
#define BS (BATCH*SEQ)   // 32768
#define PCOL 2051

typedef unsigned short ushort_t;
typedef __attribute__((ext_vector_type(8))) short short8;
typedef __attribute__((ext_vector_type(4))) float f32x4;
typedef __attribute__((ext_vector_type(4))) unsigned short us4;

__device__ __forceinline__ float bf2f(ushort_t u) {
    union { unsigned u32; float f; } v; v.u32 = ((unsigned)u) << 16; return v.f;
}
__device__ __forceinline__ ushort_t f2bf(float f) {
    union { float f; unsigned u; } v; v.f = f;
    unsigned r = v.u + 0x7fffu + ((v.u >> 16) & 1u);
    return (ushort_t)(r >> 16);
}
__device__ __forceinline__ float gelu_exact(float x) {
    return 0.5f * x * (1.0f + erff(x * 0.7071067811865475f));
}
__device__ __forceinline__ void gld16(const ushort_t* g, ushort_t* l) {
    __builtin_amdgcn_global_load_lds(
        (const __attribute__((address_space(1))) unsigned int*)g,
        (__attribute__((address_space(3))) unsigned int*)l, 16, 0, 0);
}

// ---------------- elementwise f32 -> bf16 ----------------
__global__ void cvt_f32_bf16(const float* __restrict__ src, ushort_t* __restrict__ dst, int n) {
    int i = (blockIdx.x * 256 + threadIdx.x) * 4;
    if (i >= n) return;
    f32x4 v = *(const f32x4*)(src + i);
    us4 o;
    #pragma unroll
    for (int j = 0; j < 4; j++) o[j] = f2bf(v[j]);
    *(us4*)(dst + i) = o;
}

// ---------------- transpose + cvt: dst[n*K + k] = src[k*ld + n], n in [0, 32*gridDim.x) ----------------
__global__ void transpose_cvt(const float* __restrict__ src, ushort_t* __restrict__ dst,
                              int ld, int K) {
    __shared__ float tile[32][33];
    int tx = threadIdx.x & 31, ty = threadIdx.x >> 5;   // 32 x 8
    int n0 = blockIdx.x * 32, k0 = blockIdx.y * 32;
    #pragma unroll
    for (int j = 0; j < 4; j++)
        tile[ty + j * 8][tx] = src[(size_t)(k0 + ty + j * 8) * ld + n0 + tx];
    __syncthreads();
    #pragma unroll
    for (int j = 0; j < 4; j++)
        dst[(size_t)(n0 + ty + j * 8) * K + k0 + tx] = f2bf(tile[tx][ty + j * 8]);
}

// ---------------- bf16 MFMA GEMM: C[M,N] = A[M,K] @ Bt[N,K]^T + bias ----------------
// 128x128 tile, 256 thr (4 waves, 2x2), each wave 4x4 MFMA 16x16x32.
template<int FUSEQ, int F32OUT>
__global__ __launch_bounds__(256, 2)
void gemm_bt(const ushort_t* __restrict__ A, const ushort_t* __restrict__ Bt,
             const float* __restrict__ bias, void* __restrict__ C,
             const ushort_t* __restrict__ Q, int K, int ldc, int ldq) {
    __shared__ ushort_t lA[128 * 32];
    __shared__ ushort_t lB[128 * 32];
    const int tid = threadIdx.x, lane = tid & 63, wave = tid >> 6;
    const int bn = blockIdx.x, bm = blockIdx.y;
    const int wm = (wave >> 1) * 64, wn = (wave & 1) * 64;
    const int lr = lane & 15, kq = (lane >> 4) * 8;

    const ushort_t* Ag = A + (size_t)bm * 128 * K;
    const ushort_t* Bg = Bt + (size_t)bn * 128 * K;

    f32x4 acc[4][4];
    #pragma unroll
    for (int i = 0; i < 4; i++)
        #pragma unroll
        for (int j = 0; j < 4; j++)
            #pragma unroll
            for (int r = 0; r < 4; r++) acc[i][j][r] = 0.0f;

    for (int k0 = 0; k0 < K; k0 += 32) {
        #pragma unroll
        for (int i = 0; i < 2; i++) {
            int cb = i * 256 + wave * 64;        // wave-uniform chunk base
            int c  = cb + lane;                  // 16B chunk id; row = c/4, k = (c%4)*8
            int row = c >> 2, kk = (c & 3) << 3;
            gld16(Ag + (size_t)row * K + kk, &lA[cb << 3]);
            gld16(Bg + (size_t)row * K + kk, &lB[cb << 3]);
        }
        Ag += 32; Bg += 32;
        __syncthreads();

        short8 af[4], bfr[4];
        #pragma unroll
        for (int mt = 0; mt < 4; mt++)
            af[mt] = *(const short8*)&lA[(wm + mt * 16 + lr) * 32 + kq];
        #pragma unroll
        for (int nt = 0; nt < 4; nt++)
            bfr[nt] = *(const short8*)&lB[(wn + nt * 16 + lr) * 32 + kq];
        #pragma unroll
        for (int mt = 0; mt < 4; mt++)
            #pragma unroll
            for (int nt = 0; nt < 4; nt++)
                acc[mt][nt] = __builtin_amdgcn_mfma_f32_16x16x32_bf16(
                    af[mt], bfr[nt], acc[mt][nt], 0, 0, 0);
        __syncthreads();
    }

    const int lq = lane >> 4;
    #pragma unroll
    for (int mt = 0; mt < 4; mt++) {
        #pragma unroll
        for (int r = 0; r < 4; r++) {
            int row = bm * 128 + wm + mt * 16 + lq * 4 + r;
            size_t rowc = (size_t)row * ldc;
            #pragma unroll
            for (int nt = 0; nt < 4; nt++) {
                int col = bn * 128 + wn + nt * 16 + lr;
                float v = acc[mt][nt][r] + bias[col];
                if (FUSEQ) v *= bf2f(Q[(size_t)row * ldq + col]);
                if (F32OUT) ((float*)C)[rowc + col] = v;
                else        ((ushort_t*)C)[rowc + col] = f2bf(v);
            }
        }
    }
}

// ---------------- gates GEMV: gates[row][j] = input_bf16[row,:] . W_in[:, 2048+j] + b_in ----------------
__global__ void gates_kernel(const ushort_t* __restrict__ X, const float* __restrict__ W_in,
                             const float* __restrict__ b_in, float* __restrict__ gates) {
    __shared__ float wl[3][1024];
    int tid = threadIdx.x;
    for (int d = tid; d < 1024; d += 256) {
        const float* p = W_in + (size_t)d * PCOL + 2048;
        wl[0][d] = p[0]; wl[1][d] = p[1]; wl[2][d] = p[2];
    }
    __syncthreads();
    int wave = tid >> 6, lane = tid & 63;
    int row = blockIdx.x * 4 + wave;
    const ushort_t* x = X + (size_t)row * 1024;
    float a0 = 0, a1 = 0, a2 = 0;
    #pragma unroll
    for (int i = 0; i < 16; i++) {
        int d = i * 64 + lane;
        float xv = bf2f(x[d]);
        a0 += xv * wl[0][d]; a1 += xv * wl[1][d]; a2 += xv * wl[2][d];
    }
    #pragma unroll
    for (int off = 32; off; off >>= 1) {
        a0 += __shfl_down(a0, off, 64);
        a1 += __shfl_down(a1, off, 64);
        a2 += __shfl_down(a2, off, 64);
    }
    if (lane == 0) {
        gates[row * 4 + 0] = a0 + b_in[2048];
        gates[row * 4 + 1] = a1 + b_in[2049];
        gates[row * 4 + 2] = a2 + b_in[2050];
    }
}

// ---------------- depthwise conv (along s) + exact gelu, (B,S,D)-layout ----------------
template<int KW, int PADL>
__global__ void dwconv_gelu_kernel(const ushort_t* __restrict__ X, int ldx, int x0,
                                   const float* __restrict__ W, const float* __restrict__ Bv,
                                   ushort_t* __restrict__ Y) {
    const int R = 64 + KW - 1;
    __shared__ float xs[(64 + KW - 1) * 64];
    __shared__ float wk[64 * KW];
    __shared__ float bk[64];
    int tid = threadIdx.x;
    int s0 = blockIdx.x * 64, d0 = blockIdx.y * 64, b = blockIdx.z;
    for (int idx = tid; idx < R * 64; idx += 256) {
        int r = idx >> 6, d = idx & 63;
        int s = s0 + r - PADL;
        float v = 0.f;
        if (s >= 0 && s < SEQ) v = bf2f(X[(size_t)(b * SEQ + s) * ldx + x0 + d0 + d]);
        xs[idx] = v;
    }
    for (int idx = tid; idx < 64 * KW; idx += 256)
        wk[idx] = W[(size_t)(d0 + idx / KW) * KW + idx % KW];
    if (tid < 64) bk[tid] = Bv[d0 + tid];
    __syncthreads();
    int d = tid & 63, so = tid >> 6;
    for (int i = 0; i < 16; i++) {
        int sl = so * 16 + i;
        float acc = bk[d];
        #pragma unroll
        for (int t = 0; t < KW; t++) acc += xs[(sl + t) * 64 + d] * wk[d * KW + t];
        Y[(size_t)(b * SEQ + s0 + sl) * 1024 + d0 + d] = f2bf(gelu_exact(acc));
    }
}

// ---------------- g[b,d] = gelu(mean_s c1[b,s,d]) ----------------
__global__ void meang_kernel(const ushort_t* __restrict__ C1, float* __restrict__ G) {
    __shared__ float red[4 * 64];
    int tid = threadIdx.x, d = tid & 63, so = tid >> 6;
    int d0 = blockIdx.x * 64, b = blockIdx.y;
    float acc = 0.f;
    for (int i = 0; i < 1024; i++) {
        int s = i * 4 + so;
        acc += bf2f(C1[(size_t)(b * SEQ + s) * 1024 + d0 + d]);
    }
    red[so * 64 + d] = acc;
    __syncthreads();
    if (so == 0) {
        float t = red[d] + red[64 + d] + red[128 + d] + red[192 + d];
        G[b * 1024 + d0 + d] = gelu_exact(t * (1.0f / 4096.0f));
    }
}

// ---------------- context_all = c0*g0 + c1*g1 + g*g2 (bf16 out) ----------------
__global__ void combine_kernel(const ushort_t* __restrict__ C0, const ushort_t* __restrict__ C1,
                               const float* __restrict__ gates, const float* __restrict__ G,
                               ushort_t* __restrict__ CA) {
    int row = blockIdx.x;
    int b = row >> 12;
    int c = threadIdx.x * 4;
    float g0 = gates[row * 4 + 0], g1 = gates[row * 4 + 1], g2 = gates[row * 4 + 2];
    size_t base = (size_t)row * 1024 + c;
    us4 u0 = *(const us4*)&C0[base];
    us4 u1 = *(const us4*)&C1[base];
    f32x4 gv = *(const f32x4*)&G[b * 1024 + c];
    us4 o;
    #pragma unroll
    for (int j = 0; j < 4; j++) {
        float v = bf2f(u0[j]) * g0 + bf2f(u1[j]) * g1 + gv[j] * g2;
        o[j] = f2bf(v);
    }
    *(us4*)&CA[base] = o;
}

extern "C" void kernel_launch(void* const* d_in, const int* in_sizes, int n_in,
                              void* d_out, int out_size, void* d_ws, size_t ws_size,
                              hipStream_t stream) {
    const float* input = (const float*)d_in[0];
    const float* W_in  = (const float*)d_in[1];
    const float* b_in  = (const float*)d_in[2];
    const float* w0    = (const float*)d_in[3];
    const float* b0    = (const float*)d_in[4];
    const float* w1    = (const float*)d_in[5];
    const float* b1    = (const float*)d_in[6];
    const float* W_ctx = (const float*)d_in[7];
    const float* b_ctx = (const float*)d_in[8];
    const float* W_out = (const float*)d_in[9];
    const float* b_out = (const float*)d_in[10];

    char* ws = (char*)d_ws;
    size_t o = 0;
    ushort_t* ibf   = (ushort_t*)(ws + o); o += (size_t)BS * 1024 * 2;   // input bf16, later reused as ca
    ushort_t* proj  = (ushort_t*)(ws + o); o += (size_t)BS * 2048 * 2;   // [query | ctx] bf16
    ushort_t* c0    = (ushort_t*)(ws + o); o += (size_t)BS * 1024 * 2;   // later reused as Y
    ushort_t* c1    = (ushort_t*)(ws + o); o += (size_t)BS * 1024 * 2;
    float*    gates = (float*)   (ws + o); o += (size_t)BS * 4 * 4;
    float*    g     = (float*)   (ws + o); o += (size_t)BATCH * 1024 * 4;
    ushort_t* winT  = (ushort_t*)(ws + o); o += (size_t)2048 * 1024 * 2;
    ushort_t* wctxB = (ushort_t*)(ws + o); o += (size_t)1024 * 1024 * 2;
    ushort_t* woutT = (ushort_t*)(ws + o); o += (size_t)1024 * 1024 * 2;
    ushort_t* ca = ibf;   // safe: ibf last read by gemm1/gates, combine writes after
    ushort_t* Y  = c0;    // safe: c0 last read by combine, gemm2 writes after

    // weight prep (cheap, one-time per launch)
    cvt_f32_bf16<<<BS * 1024 / 4 / 256, 256, 0, stream>>>(input, ibf, BS * 1024);
    transpose_cvt<<<dim3(2048 / 32, 1024 / 32), 256, 0, stream>>>(W_in, winT, PCOL, 1024);
    cvt_f32_bf16<<<1024 * 1024 / 4 / 256, 256, 0, stream>>>(W_ctx, wctxB, 1024 * 1024);
    transpose_cvt<<<dim3(1024 / 32, 1024 / 32), 256, 0, stream>>>(W_out, woutT, 1024, 1024);

    // proj[:, 0:2048] = input @ W_in[:, 0:2048] + b_in
    gemm_bt<0, 0><<<dim3(16, 256), 256, 0, stream>>>(ibf, winT, b_in, proj, nullptr, 1024, 2048, 0);
    // gates (cols 2048..2050)
    gates_kernel<<<BS / 4, 256, 0, stream>>>(ibf, W_in, b_in, gates);
    // c0 = gelu(dwconv14(ctx)), ctx = proj cols [1024,2048)
    dwconv_gelu_kernel<14, 6><<<dim3(SEQ / 64, 16, BATCH), 256, 0, stream>>>(proj, 2048, 1024, w0, b0, c0);
    // c1 = gelu(dwconv18(c0))
    dwconv_gelu_kernel<18, 8><<<dim3(SEQ / 64, 16, BATCH), 256, 0, stream>>>(c0, 1024, 0, w1, b1, c1);
    // g = gelu(mean_s c1)
    meang_kernel<<<dim3(16, BATCH), 256, 0, stream>>>(c1, g);
    // context_all
    combine_kernel<<<BS, 256, 0, stream>>>(c0, c1, gates, g, ca);
    // Y = query * (ca @ W_ctx^T + b_ctx)   (fused epilogue; query = proj cols [0,1024))
    gemm_bt<1, 0><<<dim3(8, 256), 256, 0, stream>>>(ca, wctxB, b_ctx, Y, proj, 1024, 1024, 2048);
    // out = Y @ W_out + b_out  (fp32)
    gemm_bt<0, 1><<<dim3(8, 256), 256, 0, stream>>>(Y, woutT, b_out, d_out, nullptr, 1024, 1024, 0);
}

// Round 2
// 760.476 us; speedup vs baseline: 1.1793x; 1.1793x over previous
//
#include <hip/hip_runtime.h>

#define DIMC 1024
#define BATCH 8
#define SEQ 4096
#define BS (BATCH*SEQ)   // 32768
#define PCOL 2051

typedef unsigned short ushort_t;
typedef __attribute__((ext_vector_type(8))) short short8;
typedef __attribute__((ext_vector_type(4))) float f32x4;
typedef __attribute__((ext_vector_type(4))) unsigned short us4;

__device__ __forceinline__ float bf2f(ushort_t u) {
    union { unsigned u32; float f; } v; v.u32 = ((unsigned)u) << 16; return v.f;
}
__device__ __forceinline__ ushort_t f2bf(float f) {
    union { float f; unsigned u; } v; v.f = f;
    unsigned r = v.u + 0x7fffu + ((v.u >> 16) & 1u);
    return (ushort_t)(r >> 16);
}
__device__ __forceinline__ float gelu_exact(float x) {
    return 0.5f * x * (1.0f + erff(x * 0.7071067811865475f));
}
__device__ __forceinline__ void gld16(const ushort_t* g, ushort_t* l) {
    __builtin_amdgcn_global_load_lds(
        (const __attribute__((address_space(1))) unsigned int*)g,
        (__attribute__((address_space(3))) unsigned int*)l, 16, 0, 0);
}

// ---------------- elementwise f32 -> bf16 ----------------
__global__ void cvt_f32_bf16(const float* __restrict__ src, ushort_t* __restrict__ dst, int n) {
    int i = (blockIdx.x * 256 + threadIdx.x) * 4;
    if (i >= n) return;
    f32x4 v = *(const f32x4*)(src + i);
    us4 o;
    #pragma unroll
    for (int j = 0; j < 4; j++) o[j] = f2bf(v[j]);
    *(us4*)(dst + i) = o;
}

// ---------------- transpose + cvt: dst[n*K + k] = src[k*ld + n] ----------------
__global__ void transpose_cvt(const float* __restrict__ src, ushort_t* __restrict__ dst,
                              int ld, int K) {
    __shared__ float tile[32][33];
    int tx = threadIdx.x & 31, ty = threadIdx.x >> 5;   // 32 x 8
    int n0 = blockIdx.x * 32, k0 = blockIdx.y * 32;
    #pragma unroll
    for (int j = 0; j < 4; j++)
        tile[ty + j * 8][tx] = src[(size_t)(k0 + ty + j * 8) * ld + n0 + tx];
    __syncthreads();
    #pragma unroll
    for (int j = 0; j < 4; j++)
        dst[(size_t)(n0 + ty + j * 8) * K + k0 + tx] = f2bf(tile[tx][ty + j * 8]);
}

// ---------------- pack gate weight columns: wg[j*1024+d] = W_in[d*PCOL + 2048+j] ----------------
__global__ void pack_gatesw(const float* __restrict__ W_in, float* __restrict__ wg) {
    int d = blockIdx.x * 256 + threadIdx.x;
    if (d >= 1024) return;
    const float* p = W_in + (size_t)d * PCOL + 2048;
    wg[d] = p[0]; wg[1024 + d] = p[1]; wg[2048 + d] = p[2];
}

// ---------------- fused: ibf = bf16(input); gates[row] = input[row] . wg + b_in ----------------
__global__ void cvt_gates(const float* __restrict__ input, const float* __restrict__ wg,
                          const float* __restrict__ b_in, ushort_t* __restrict__ ibf,
                          float* __restrict__ gates) {
    int row = blockIdx.x, tid = threadIdx.x;
    int lane = tid & 63, wave = tid >> 6;
    size_t base = (size_t)row * 1024 + tid * 4;
    f32x4 v = *(const f32x4*)(input + base);
    us4 o;
    #pragma unroll
    for (int j = 0; j < 4; j++) o[j] = f2bf(v[j]);
    *(us4*)(ibf + base) = o;
    f32x4 w0v = *(const f32x4*)(wg + tid * 4);
    f32x4 w1v = *(const f32x4*)(wg + 1024 + tid * 4);
    f32x4 w2v = *(const f32x4*)(wg + 2048 + tid * 4);
    float a0 = 0, a1 = 0, a2 = 0;
    #pragma unroll
    for (int j = 0; j < 4; j++) { a0 += v[j] * w0v[j]; a1 += v[j] * w1v[j]; a2 += v[j] * w2v[j]; }
    #pragma unroll
    for (int off = 32; off; off >>= 1) {
        a0 += __shfl_down(a0, off, 64);
        a1 += __shfl_down(a1, off, 64);
        a2 += __shfl_down(a2, off, 64);
    }
    __shared__ float red[4][3];
    if (lane == 0) { red[wave][0] = a0; red[wave][1] = a1; red[wave][2] = a2; }
    __syncthreads();
    if (tid == 0) {
        gates[row * 4 + 0] = red[0][0] + red[1][0] + red[2][0] + red[3][0] + b_in[2048];
        gates[row * 4 + 1] = red[0][1] + red[1][1] + red[2][1] + red[3][1] + b_in[2049];
        gates[row * 4 + 2] = red[0][2] + red[1][2] + red[2][2] + red[3][2] + b_in[2050];
    }
}

// ---------------- bf16 MFMA GEMM: C[M,N] = A[M,K] @ Bt[N,K]^T + bias ----------------
template<int FUSEQ, int F32OUT>
__global__ __launch_bounds__(256, 2)
void gemm_bt(const ushort_t* __restrict__ A, const ushort_t* __restrict__ Bt,
             const float* __restrict__ bias, void* __restrict__ C,
             const ushort_t* __restrict__ Q, int K, int ldc, int ldq) {
    __shared__ ushort_t lA[128 * 32];
    __shared__ ushort_t lB[128 * 32];
    const int tid = threadIdx.x, lane = tid & 63, wave = tid >> 6;
    const int bn = blockIdx.x, bm = blockIdx.y;
    const int wm = (wave >> 1) * 64, wn = (wave & 1) * 64;
    const int lr = lane & 15, kq = (lane >> 4) * 8;

    const ushort_t* Ag = A + (size_t)bm * 128 * K;
    const ushort_t* Bg = Bt + (size_t)bn * 128 * K;

    f32x4 acc[4][4];
    #pragma unroll
    for (int i = 0; i < 4; i++)
        #pragma unroll
        for (int j = 0; j < 4; j++)
            #pragma unroll
            for (int r = 0; r < 4; r++) acc[i][j][r] = 0.0f;

    for (int k0 = 0; k0 < K; k0 += 32) {
        #pragma unroll
        for (int i = 0; i < 2; i++) {
            int cb = i * 256 + wave * 64;        // wave-uniform chunk base
            int c  = cb + lane;                  // 16B chunk id; row = c/4, k = (c%4)*8
            int row = c >> 2, kk = (c & 3) << 3;
            gld16(Ag + (size_t)row * K + kk, &lA[cb << 3]);
            gld16(Bg + (size_t)row * K + kk, &lB[cb << 3]);
        }
        Ag += 32; Bg += 32;
        __syncthreads();

        short8 af[4], bfr[4];
        #pragma unroll
        for (int mt = 0; mt < 4; mt++)
            af[mt] = *(const short8*)&lA[(wm + mt * 16 + lr) * 32 + kq];
        #pragma unroll
        for (int nt = 0; nt < 4; nt++)
            bfr[nt] = *(const short8*)&lB[(wn + nt * 16 + lr) * 32 + kq];
        #pragma unroll
        for (int mt = 0; mt < 4; mt++)
            #pragma unroll
            for (int nt = 0; nt < 4; nt++)
                acc[mt][nt] = __builtin_amdgcn_mfma_f32_16x16x32_bf16(
                    af[mt], bfr[nt], acc[mt][nt], 0, 0, 0);
        __syncthreads();
    }

    const int lq = lane >> 4;
    #pragma unroll
    for (int mt = 0; mt < 4; mt++) {
        #pragma unroll
        for (int r = 0; r < 4; r++) {
            int row = bm * 128 + wm + mt * 16 + lq * 4 + r;
            size_t rowc = (size_t)row * ldc;
            #pragma unroll
            for (int nt = 0; nt < 4; nt++) {
                int col = bn * 128 + wn + nt * 16 + lr;
                float v = acc[mt][nt][r] + bias[col];
                if (FUSEQ) v *= bf2f(Q[(size_t)row * ldq + col]);
                if (F32OUT) ((float*)C)[rowc + col] = v;
                else        ((ushort_t*)C)[rowc + col] = f2bf(v);
            }
        }
    }
}

// ---------------- depthwise conv (along s) + exact gelu; optional mean accumulation ----------------
// block: 64 s x 64 d; staging vectorized (short8); taps in registers (sliding window).
template<int KW, int PADL, int DOMEAN>
__global__ __launch_bounds__(256)
void dwconv_gelu2(const ushort_t* __restrict__ X, int ldx, int x0,
                  const float* __restrict__ W, const float* __restrict__ Bv,
                  ushort_t* __restrict__ Y, float* __restrict__ G) {
    const int R = 64 + KW - 1;
    __shared__ float xs[(64 + KW - 1) * 64];
    int tid = threadIdx.x;
    int s0 = blockIdx.x * 64, d0 = blockIdx.y * 64, b = blockIdx.z;
    // stage R rows x 64 d (bf16 -> f32), 8 elems per chunk
    for (int c = tid; c < R * 8; c += 256) {
        int r = c >> 3, dd = (c & 7) * 8;
        int s = s0 + r - PADL;
        float f[8];
        if (s >= 0 && s < SEQ) {
            short8 u = *(const short8*)&X[(size_t)(b * SEQ + s) * ldx + x0 + d0 + dd];
            #pragma unroll
            for (int j = 0; j < 8; j++) f[j] = bf2f((ushort_t)u[j]);
        } else {
            #pragma unroll
            for (int j = 0; j < 8; j++) f[j] = 0.f;
        }
        f32x4 v0 = {f[0], f[1], f[2], f[3]}, v1 = {f[4], f[5], f[6], f[7]};
        *(f32x4*)&xs[r * 64 + dd] = v0;
        *(f32x4*)&xs[r * 64 + dd + 4] = v1;
    }
    int d = tid & 63, sc = tid >> 6;      // thread owns column d, s-chunk sc*16..+15
    float wr[KW];
    #pragma unroll
    for (int t = 0; t < KW; t++) wr[t] = W[(size_t)(d0 + d) * KW + t];
    float bb = Bv[d0 + d];
    __syncthreads();
    float xw[16 + KW - 1];
    #pragma unroll
    for (int r = 0; r < 16 + KW - 1; r++) xw[r] = xs[(sc * 16 + r) * 64 + d];
    float psum = 0.f;
    #pragma unroll
    for (int i = 0; i < 16; i++) {
        float acc = bb;
        #pragma unroll
        for (int t = 0; t < KW; t++) acc += wr[t] * xw[i + t];
        float gv = gelu_exact(acc);
        if (DOMEAN) psum += gv;
        Y[(size_t)(b * SEQ + s0 + sc * 16 + i) * 1024 + d0 + d] = f2bf(gv);
    }
    if (DOMEAN) {
        __shared__ float rs[256];
        rs[tid] = psum;
        __syncthreads();
        if (sc == 0)
            atomicAdd(&G[b * 1024 + d0 + d], rs[d] + rs[64 + d] + rs[128 + d] + rs[192 + d]);
    }
}

// ---------------- gG = gelu(G / SEQ) ----------------
__global__ void gelu_g(const float* __restrict__ G, float* __restrict__ gG) {
    int i = blockIdx.x * 256 + threadIdx.x;
    if (i < BATCH * 1024) gG[i] = gelu_exact(G[i] * (1.0f / (float)SEQ));
}

// ---------------- context_all = c0*g0 + c1*g1 + gG*g2 (bf16 out), 16B/lane ----------------
__global__ void combine2(const ushort_t* __restrict__ C0, const ushort_t* __restrict__ C1,
                         const float* __restrict__ gates, const float* __restrict__ gG,
                         ushort_t* __restrict__ CA) {
    int row = blockIdx.x * 2 + (threadIdx.x >> 7);
    int c = (threadIdx.x & 127) * 8;
    int b = row >> 12;
    float g0 = gates[row * 4 + 0], g1 = gates[row * 4 + 1], g2 = gates[row * 4 + 2];
    size_t base = (size_t)row * 1024 + c;
    short8 u0 = *(const short8*)&C0[base];
    short8 u1 = *(const short8*)&C1[base];
    f32x4 gv0 = *(const f32x4*)&gG[b * 1024 + c];
    f32x4 gv1 = *(const f32x4*)&gG[b * 1024 + c + 4];
    short8 o;
    #pragma unroll
    for (int j = 0; j < 8; j++) {
        float gg = (j < 4) ? gv0[j] : gv1[j - 4];
        float v = bf2f((ushort_t)u0[j]) * g0 + bf2f((ushort_t)u1[j]) * g1 + gg * g2;
        o[j] = (short)f2bf(v);
    }
    *(short8*)&CA[base] = o;
}

extern "C" void kernel_launch(void* const* d_in, const int* in_sizes, int n_in,
                              void* d_out, int out_size, void* d_ws, size_t ws_size,
                              hipStream_t stream) {
    const float* input = (const float*)d_in[0];
    const float* W_in  = (const float*)d_in[1];
    const float* b_in  = (const float*)d_in[2];
    const float* w0    = (const float*)d_in[3];
    const float* b0    = (const float*)d_in[4];
    const float* w1    = (const float*)d_in[5];
    const float* b1    = (const float*)d_in[6];
    const float* W_ctx = (const float*)d_in[7];
    const float* b_ctx = (const float*)d_in[8];
    const float* W_out = (const float*)d_in[9];
    const float* b_out = (const float*)d_in[10];

    char* ws = (char*)d_ws;
    size_t o = 0;
    ushort_t* ibf   = (ushort_t*)(ws + o); o += (size_t)BS * 1024 * 2;   // input bf16, reused as ca
    ushort_t* proj  = (ushort_t*)(ws + o); o += (size_t)BS * 2048 * 2;   // [query | ctx] bf16
    ushort_t* c0    = (ushort_t*)(ws + o); o += (size_t)BS * 1024 * 2;   // reused as Y
    ushort_t* c1    = (ushort_t*)(ws + o); o += (size_t)BS * 1024 * 2;
    float*    gates = (float*)   (ws + o); o += (size_t)BS * 4 * 4;
    float*    G     = (float*)   (ws + o); o += (size_t)BATCH * 1024 * 4;
    float*    gG    = (float*)   (ws + o); o += (size_t)BATCH * 1024 * 4;
    float*    wg    = (float*)   (ws + o); o += (size_t)3 * 1024 * 4;
    ushort_t* winT  = (ushort_t*)(ws + o); o += (size_t)2048 * 1024 * 2;
    ushort_t* wctxB = (ushort_t*)(ws + o); o += (size_t)1024 * 1024 * 2;
    ushort_t* woutT = (ushort_t*)(ws + o); o += (size_t)1024 * 1024 * 2;
    ushort_t* ca = ibf;   // safe: ibf last read by gemm1; combine writes after
    ushort_t* Y  = c0;    // safe: c0 last read by combine; gemm2 writes after

    hipMemsetAsync(G, 0, BATCH * 1024 * sizeof(float), stream);
    // weight prep
    pack_gatesw<<<4, 256, 0, stream>>>(W_in, wg);
    transpose_cvt<<<dim3(2048 / 32, 1024 / 32), 256, 0, stream>>>(W_in, winT, PCOL, 1024);
    cvt_f32_bf16<<<1024 * 1024 / 4 / 256, 256, 0, stream>>>(W_ctx, wctxB, 1024 * 1024);
    transpose_cvt<<<dim3(1024 / 32, 1024 / 32), 256, 0, stream>>>(W_out, woutT, 1024, 1024);
    // input cvt + gates GEMV (fp32 accuracy)
    cvt_gates<<<BS, 256, 0, stream>>>(input, wg, b_in, ibf, gates);
    // proj[:, 0:2048] = input @ W_in[:, 0:2048] + b_in
    gemm_bt<0, 0><<<dim3(16, 256), 256, 0, stream>>>(ibf, winT, b_in, proj, nullptr, 1024, 2048, 0);
    // c0 = gelu(dwconv14(ctx)), ctx = proj cols [1024,2048)
    dwconv_gelu2<14, 6, 0><<<dim3(SEQ / 64, 16, BATCH), 256, 0, stream>>>(proj, 2048, 1024, w0, b0, c0, nullptr);
    // c1 = gelu(dwconv18(c0)) + per-(b,d) sum accumulation
    dwconv_gelu2<18, 8, 1><<<dim3(SEQ / 64, 16, BATCH), 256, 0, stream>>>(c0, 1024, 0, w1, b1, c1, G);
    // gG = gelu(mean)
    gelu_g<<<BATCH * 1024 / 256, 256, 0, stream>>>(G, gG);
    // context_all
    combine2<<<BS / 2, 256, 0, stream>>>(c0, c1, gates, gG, ca);
    // Y = query * (ca @ W_ctx^T + b_ctx)
    gemm_bt<1, 0><<<dim3(8, 256), 256, 0, stream>>>(ca, wctxB, b_ctx, Y, proj, 1024, 1024, 2048);
    // out = Y @ W_out + b_out  (fp32)
    gemm_bt<0, 1><<<dim3(8, 256), 256, 0, stream>>>(Y, woutT, b_out, d_out, nullptr, 1024, 1024, 0);
}

// Round 3
// 735.865 us; speedup vs baseline: 1.2187x; 1.0334x over previous
//
#include <hip/hip_runtime.h>

#define DIMC 1024
#define BATCH 8
#define SEQ 4096
#define BS (BATCH*SEQ)   // 32768
#define PCOL 2051

typedef unsigned short ushort_t;
typedef __attribute__((ext_vector_type(8))) short short8;
typedef __attribute__((ext_vector_type(4))) float f32x4;
typedef __attribute__((ext_vector_type(4))) unsigned short us4;

__device__ __forceinline__ float bf2f(ushort_t u) {
    union { unsigned u32; float f; } v; v.u32 = ((unsigned)u) << 16; return v.f;
}
__device__ __forceinline__ ushort_t f2bf(float f) {
    union { float f; unsigned u; } v; v.f = f;
    unsigned r = v.u + 0x7fffu + ((v.u >> 16) & 1u);
    return (ushort_t)(r >> 16);
}
__device__ __forceinline__ float gelu_exact(float x) {
    return 0.5f * x * (1.0f + erff(x * 0.7071067811865475f));
}
__device__ __forceinline__ void gld16(const ushort_t* g, ushort_t* l) {
    __builtin_amdgcn_global_load_lds(
        (const __attribute__((address_space(1))) unsigned int*)g,
        (__attribute__((address_space(3))) unsigned int*)l, 16, 0, 0);
}

// ---------------- elementwise f32 -> bf16 ----------------
__global__ void cvt_f32_bf16(const float* __restrict__ src, ushort_t* __restrict__ dst, int n) {
    int i = (blockIdx.x * 256 + threadIdx.x) * 4;
    if (i >= n) return;
    f32x4 v = *(const f32x4*)(src + i);
    us4 o;
    #pragma unroll
    for (int j = 0; j < 4; j++) o[j] = f2bf(v[j]);
    *(us4*)(dst + i) = o;
}

// ---------------- transpose + cvt: dst[n*K + k] = src[k*ld + n] ----------------
__global__ void transpose_cvt(const float* __restrict__ src, ushort_t* __restrict__ dst,
                              int ld, int K) {
    __shared__ float tile[32][33];
    int tx = threadIdx.x & 31, ty = threadIdx.x >> 5;   // 32 x 8
    int n0 = blockIdx.x * 32, k0 = blockIdx.y * 32;
    #pragma unroll
    for (int j = 0; j < 4; j++)
        tile[ty + j * 8][tx] = src[(size_t)(k0 + ty + j * 8) * ld + n0 + tx];
    __syncthreads();
    #pragma unroll
    for (int j = 0; j < 4; j++)
        dst[(size_t)(n0 + ty + j * 8) * K + k0 + tx] = f2bf(tile[tx][ty + j * 8]);
}

// ---------------- pack gate weight columns: wg[j*1024+d] = W_in[d*PCOL + 2048+j] ----------------
__global__ void pack_gatesw(const float* __restrict__ W_in, float* __restrict__ wg) {
    int d = blockIdx.x * 256 + threadIdx.x;
    if (d >= 1024) return;
    const float* p = W_in + (size_t)d * PCOL + 2048;
    wg[d] = p[0]; wg[1024 + d] = p[1]; wg[2048 + d] = p[2];
}

// ---------------- fused: ibf = bf16(input); gates[row] = input[row] . wg + b_in ----------------
__global__ void cvt_gates(const float* __restrict__ input, const float* __restrict__ wg,
                          const float* __restrict__ b_in, ushort_t* __restrict__ ibf,
                          float* __restrict__ gates) {
    int row = blockIdx.x, tid = threadIdx.x;
    int lane = tid & 63, wave = tid >> 6;
    size_t base = (size_t)row * 1024 + tid * 4;
    f32x4 v = *(const f32x4*)(input + base);
    us4 o;
    #pragma unroll
    for (int j = 0; j < 4; j++) o[j] = f2bf(v[j]);
    *(us4*)(ibf + base) = o;
    f32x4 w0v = *(const f32x4*)(wg + tid * 4);
    f32x4 w1v = *(const f32x4*)(wg + 1024 + tid * 4);
    f32x4 w2v = *(const f32x4*)(wg + 2048 + tid * 4);
    float a0 = 0, a1 = 0, a2 = 0;
    #pragma unroll
    for (int j = 0; j < 4; j++) { a0 += v[j] * w0v[j]; a1 += v[j] * w1v[j]; a2 += v[j] * w2v[j]; }
    #pragma unroll
    for (int off = 32; off; off >>= 1) {
        a0 += __shfl_down(a0, off, 64);
        a1 += __shfl_down(a1, off, 64);
        a2 += __shfl_down(a2, off, 64);
    }
    __shared__ float red[4][3];
    if (lane == 0) { red[wave][0] = a0; red[wave][1] = a1; red[wave][2] = a2; }
    __syncthreads();
    if (tid == 0) {
        gates[row * 4 + 0] = red[0][0] + red[1][0] + red[2][0] + red[3][0] + b_in[2048];
        gates[row * 4 + 1] = red[0][1] + red[1][1] + red[2][1] + red[3][1] + b_in[2049];
        gates[row * 4 + 2] = red[0][2] + red[1][2] + red[2][2] + red[3][2] + b_in[2050];
    }
}

// ---------------- bf16 MFMA GEMM: C[M,N] = A[M,K] @ Bt[N,K]^T + bias ----------------
// MODE 0: bf16 out, +bias. MODE 1: bf16 out, (acc+bias+g2[row]*v[b][col]) * Q[row,col].
// MODE 2: f32 out, +bias.
template<int MODE>
__global__ __launch_bounds__(256, 2)
void gemm_bt(const ushort_t* __restrict__ A, const ushort_t* __restrict__ Bt,
             const float* __restrict__ bias, void* __restrict__ C,
             const ushort_t* __restrict__ Q, const float* __restrict__ gates,
             const float* __restrict__ vb, int K, int ldc, int ldq) {
    __shared__ ushort_t lA[128 * 32];
    __shared__ ushort_t lB[128 * 32];
    const int tid = threadIdx.x, lane = tid & 63, wave = tid >> 6;
    const int bn = blockIdx.x, bm = blockIdx.y;
    const int wm = (wave >> 1) * 64, wn = (wave & 1) * 64;
    const int lr = lane & 15, kq = (lane >> 4) * 8;

    const ushort_t* Ag = A + (size_t)bm * 128 * K;
    const ushort_t* Bg = Bt + (size_t)bn * 128 * K;

    f32x4 acc[4][4];
    #pragma unroll
    for (int i = 0; i < 4; i++)
        #pragma unroll
        for (int j = 0; j < 4; j++)
            #pragma unroll
            for (int r = 0; r < 4; r++) acc[i][j][r] = 0.0f;

    for (int k0 = 0; k0 < K; k0 += 32) {
        #pragma unroll
        for (int i = 0; i < 2; i++) {
            int cb = i * 256 + wave * 64;        // wave-uniform chunk base
            int c  = cb + lane;                  // 16B chunk id; row = c/4, k = (c%4)*8
            int row = c >> 2, kk = (c & 3) << 3;
            gld16(Ag + (size_t)row * K + kk, &lA[cb << 3]);
            gld16(Bg + (size_t)row * K + kk, &lB[cb << 3]);
        }
        Ag += 32; Bg += 32;
        __syncthreads();

        short8 af[4], bfr[4];
        #pragma unroll
        for (int mt = 0; mt < 4; mt++)
            af[mt] = *(const short8*)&lA[(wm + mt * 16 + lr) * 32 + kq];
        #pragma unroll
        for (int nt = 0; nt < 4; nt++)
            bfr[nt] = *(const short8*)&lB[(wn + nt * 16 + lr) * 32 + kq];
        #pragma unroll
        for (int mt = 0; mt < 4; mt++)
            #pragma unroll
            for (int nt = 0; nt < 4; nt++)
                acc[mt][nt] = __builtin_amdgcn_mfma_f32_16x16x32_bf16(
                    af[mt], bfr[nt], acc[mt][nt], 0, 0, 0);
        __syncthreads();
    }

    const int lq = lane >> 4;
    const int bbatch = (bm * 128) >> 12;   // batch index (uniform per block, SEQ=4096)
    #pragma unroll
    for (int mt = 0; mt < 4; mt++) {
        #pragma unroll
        for (int r = 0; r < 4; r++) {
            int row = bm * 128 + wm + mt * 16 + lq * 4 + r;
            size_t rowc = (size_t)row * ldc;
            float g2;
            if (MODE == 1) g2 = gates[row * 4 + 2];
            #pragma unroll
            for (int nt = 0; nt < 4; nt++) {
                int col = bn * 128 + wn + nt * 16 + lr;
                float v = acc[mt][nt][r] + bias[col];
                if (MODE == 1) {
                    v += g2 * vb[bbatch * 1024 + col];
                    v *= bf2f(Q[(size_t)row * ldq + col]);
                }
                if (MODE == 2) ((float*)C)[rowc + col] = v;
                else           ((ushort_t*)C)[rowc + col] = f2bf(v);
            }
        }
    }
}

// ---------------- fused dwconv14 -> gelu -> dwconv18 -> gelu -> P = c0*g0 + c1*g1 ----------------
// Also accumulates G[b,d] += sum_s c1[b,s,d].
// Block: 64 output s-rows x 64 d-cols. ctx halo rows: [s0-14, s0+79] (94). c0 rows: [s0-8, s0+72] (81).
__global__ __launch_bounds__(256)
void dwconv_fused(const ushort_t* __restrict__ proj,   // ld=2048, ctx at col offset 1024
                  const float* __restrict__ w0, const float* __restrict__ b0,
                  const float* __restrict__ w1, const float* __restrict__ b1,
                  const float* __restrict__ gates,
                  ushort_t* __restrict__ P, float* __restrict__ G) {
    __shared__ float xc[94 * 64];
    __shared__ float x0[81 * 64];
    __shared__ float gl[2][64];
    __shared__ float rs[256];
    const int tid = threadIdx.x;
    const int s0 = blockIdx.x * 64, d0 = blockIdx.y * 64, b = blockIdx.z;
    // stage ctx (bf16 -> f32), 8-wide chunks
    for (int c = tid; c < 94 * 8; c += 256) {
        int r = c >> 3, dd = (c & 7) * 8;
        int s = s0 - 14 + r;
        float f[8];
        if (s >= 0 && s < SEQ) {
            short8 u = *(const short8*)&proj[(size_t)(b * SEQ + s) * 2048 + 1024 + d0 + dd];
            #pragma unroll
            for (int j = 0; j < 8; j++) f[j] = bf2f((ushort_t)u[j]);
        } else {
            #pragma unroll
            for (int j = 0; j < 8; j++) f[j] = 0.f;
        }
        f32x4 v0 = {f[0], f[1], f[2], f[3]}, v1 = {f[4], f[5], f[6], f[7]};
        *(f32x4*)&xc[r * 64 + dd] = v0;
        *(f32x4*)&xc[r * 64 + dd + 4] = v1;
    }
    if (tid < 64) gl[0][tid] = gates[(size_t)(b * SEQ + s0 + tid) * 4 + 0];
    else if (tid < 128) gl[1][tid - 64] = gates[(size_t)(b * SEQ + s0 + tid - 64) * 4 + 1];
    const int d = tid & 63, sc = tid >> 6;
    float wr0[14], wr1[18];
    #pragma unroll
    for (int t = 0; t < 14; t++) wr0[t] = w0[(size_t)(d0 + d) * 14 + t];
    float bb0 = b0[d0 + d];
    #pragma unroll
    for (int t = 0; t < 18; t++) wr1[t] = w1[(size_t)(d0 + d) * 18 + t];
    float bb1 = b1[d0 + d];
    __syncthreads();
    // compute c0 LDS rows [sc*20, sc*20+20] (21 rows; boundary rows overlap, identical values)
    {
        float xw[34];
        int r0 = sc * 20;
        #pragma unroll
        for (int r = 0; r < 34; r++) xw[r] = xc[(r0 + r) * 64 + d];
        #pragma unroll
        for (int i = 0; i < 21; i++) {
            int rr = r0 + i;
            int s = s0 - 8 + rr;          // global s of this c0 row
            float acc = bb0;
            #pragma unroll
            for (int t = 0; t < 14; t++) acc += wr0[t] * xw[i + t];
            // conv2 pads with ZERO outside [0,SEQ): out-of-range c0 rows must be 0
            x0[rr * 64 + d] = (s >= 0 && s < SEQ) ? gelu_exact(acc) : 0.f;
        }
    }
    __syncthreads();
    // c1 rows sc*16..+15 and P
    float xw1[33];
    #pragma unroll
    for (int r = 0; r < 33; r++) xw1[r] = x0[(sc * 16 + r) * 64 + d];
    float psum = 0.f;
    #pragma unroll
    for (int i = 0; i < 16; i++) {
        float acc = bb1;
        #pragma unroll
        for (int t = 0; t < 18; t++) acc += wr1[t] * xw1[i + t];
        float c1 = gelu_exact(acc);
        psum += c1;
        float c0v = xw1[i + 8];           // c0 at global s = s0 + sc*16 + i
        int sl = sc * 16 + i;
        float pv = c0v * gl[0][sl] + c1 * gl[1][sl];
        P[(size_t)(b * SEQ + s0 + sl) * 1024 + d0 + d] = f2bf(pv);
    }
    rs[tid] = psum;
    __syncthreads();
    if (sc == 0)
        atomicAdd(&G[b * 1024 + d0 + d], rs[d] + rs[64 + d] + rs[128 + d] + rs[192 + d]);
}

// ---------------- v[b,o] = sum_c gelu(G[b,c]/SEQ) * Wctx[o,c]  (rank-1 correction row) ----------------
__global__ __launch_bounds__(256)
void gemv_v(const float* __restrict__ G, const ushort_t* __restrict__ wctxB,
            float* __restrict__ v) {
    __shared__ float gg[1024];
    const int tid = threadIdx.x, b = blockIdx.y;
    for (int i = tid; i < 1024; i += 256)
        gg[i] = gelu_exact(G[b * 1024 + i] * (1.0f / (float)SEQ));
    __syncthreads();
    const int w = tid >> 6, lane = tid & 63;
    const int o = blockIdx.x * 4 + w;
    const ushort_t* wr = wctxB + (size_t)o * 1024;
    float acc = 0.f;
    #pragma unroll
    for (int j = 0; j < 16; j++)
        acc += gg[j * 64 + lane] * bf2f(wr[j * 64 + lane]);
    #pragma unroll
    for (int off = 32; off; off >>= 1) acc += __shfl_down(acc, off, 64);
    if (lane == 0) v[b * 1024 + o] = acc;
}

extern "C" void kernel_launch(void* const* d_in, const int* in_sizes, int n_in,
                              void* d_out, int out_size, void* d_ws, size_t ws_size,
                              hipStream_t stream) {
    const float* input = (const float*)d_in[0];
    const float* W_in  = (const float*)d_in[1];
    const float* b_in  = (const float*)d_in[2];
    const float* w0    = (const float*)d_in[3];
    const float* b0    = (const float*)d_in[4];
    const float* w1    = (const float*)d_in[5];
    const float* b1    = (const float*)d_in[6];
    const float* W_ctx = (const float*)d_in[7];
    const float* b_ctx = (const float*)d_in[8];
    const float* W_out = (const float*)d_in[9];
    const float* b_out = (const float*)d_in[10];

    char* ws = (char*)d_ws;
    size_t o = 0;
    ushort_t* ibf   = (ushort_t*)(ws + o); o += (size_t)BS * 1024 * 2;   // input bf16, reused as P
    ushort_t* proj  = (ushort_t*)(ws + o); o += (size_t)BS * 2048 * 2;   // [query | ctx] bf16
    ushort_t* Y     = (ushort_t*)(ws + o); o += (size_t)BS * 1024 * 2;
    float*    gates = (float*)   (ws + o); o += (size_t)BS * 4 * 4;
    float*    G     = (float*)   (ws + o); o += (size_t)BATCH * 1024 * 4;
    float*    v     = (float*)   (ws + o); o += (size_t)BATCH * 1024 * 4;
    float*    wg    = (float*)   (ws + o); o += (size_t)3 * 1024 * 4;
    ushort_t* winT  = (ushort_t*)(ws + o); o += (size_t)2048 * 1024 * 2;
    ushort_t* wctxB = (ushort_t*)(ws + o); o += (size_t)1024 * 1024 * 2;
    ushort_t* woutT = (ushort_t*)(ws + o); o += (size_t)1024 * 1024 * 2;
    ushort_t* P = ibf;   // safe: ibf last read by gemm1; dwconv_fused writes P after

    hipMemsetAsync(G, 0, BATCH * 1024 * sizeof(float), stream);
    // weight prep
    pack_gatesw<<<4, 256, 0, stream>>>(W_in, wg);
    transpose_cvt<<<dim3(2048 / 32, 1024 / 32), 256, 0, stream>>>(W_in, winT, PCOL, 1024);
    cvt_f32_bf16<<<1024 * 1024 / 4 / 256, 256, 0, stream>>>(W_ctx, wctxB, 1024 * 1024);
    transpose_cvt<<<dim3(1024 / 32, 1024 / 32), 256, 0, stream>>>(W_out, woutT, 1024, 1024);
    // input cvt + gates GEMV (fp32)
    cvt_gates<<<BS, 256, 0, stream>>>(input, wg, b_in, ibf, gates);
    // proj[:, 0:2048] = input @ W_in[:, 0:2048] + b_in
    gemm_bt<0><<<dim3(16, 256), 256, 0, stream>>>(ibf, winT, b_in, proj, nullptr, nullptr, nullptr, 1024, 2048, 0);
    // fused conv chain -> P (= c0*g0 + c1*g1), G (= sum_s c1)
    dwconv_fused<<<dim3(SEQ / 64, 16, BATCH), 256, 0, stream>>>(proj, w0, b0, w1, b1, gates, P, G);
    // v[b,:] = gelu(G/SEQ) @ Wctx^T
    gemv_v<<<dim3(256, BATCH), 256, 0, stream>>>(G, wctxB, v);
    // Y = query * (P @ Wctx^T + b_ctx + g2 (x) v)
    gemm_bt<1><<<dim3(8, 256), 256, 0, stream>>>(P, wctxB, b_ctx, Y, proj, gates, v, 1024, 1024, 2048);
    // out = Y @ W_out + b_out  (fp32)
    gemm_bt<2><<<dim3(8, 256), 256, 0, stream>>>(Y, woutT, b_out, d_out, nullptr, nullptr, nullptr, 1024, 1024, 0);
}